// Round 2
// baseline (5886.504 us; speedup 1.0000x reference)
//
#include <hip/hip_runtime.h>
#include <hip/hip_bf16.h>

#define T_STEPS 512
#define BATCH 64
#define TB (T_STEPS * BATCH)   // 32768

typedef short bf16x8 __attribute__((ext_vector_type(8)));
typedef float f32x4 __attribute__((ext_vector_type(4)));

union FragU { uint4 u; bf16x8 v; };

static __device__ __forceinline__ bf16x8 ld_frag(const uint4* p) {
  FragU f; f.u = *p; return f.v;
}

static __device__ __forceinline__ unsigned short f2bf(float f) {
  unsigned u = __float_as_uint(f);
  return (unsigned short)((u + 0x7FFFu + ((u >> 16) & 1u)) >> 16);
}

static __device__ __forceinline__ int revrow(int r) {
  int t = r >> 6, b = r & 63;
  return ((T_STEPS - 1 - t) << 6) | b;
}

#define S_RZ  (-1.4426950408889634f)   /* -log2(e)   : sigmoid(p)=1/(1+2^(S_RZ*p)) */
#define S_C   (-2.8853900817779268f)   /* -2*log2(e) : tanh(p)=2/(1+2^(S_C*p))-1   */

// ---------------- pack weights into MFMA B-fragment layout (with gate pre-scaling) ----
// modes: 0 = X3 (768 cols, order [r|cand|z], g=n>>8), 1 = RZ (512 cols, g=n<256?0:2), 2 = C (256 cols, g=1)
__global__ void pack_w_kernel(const float* __restrict__ W, int rows, int k_base,
                              int n_tiles, int k_tiles, int mode,
                              unsigned short* __restrict__ dst) {
  int gid = blockIdx.x * blockDim.x + threadIdx.x;
  int total = n_tiles * k_tiles * 64;
  if (gid >= total) return;
  int lane = gid & 63;
  int fi = gid >> 6;
  int kt = fi % k_tiles;
  int nt = fi / k_tiles;
  int n = nt * 16 + (lane & 15);
  int g, col; float s;
  if (mode == 0)      { g = n >> 8;            col = n & 255; s = (g == 1) ? S_C : S_RZ; }
  else if (mode == 1) { g = (n < 256) ? 0 : 2; col = n & 255; s = S_RZ; }
  else                { g = 1;                 col = n;       s = S_C; }
  int k0 = k_base + kt * 32 + ((lane >> 4) << 3);
  const float* src = W + ((size_t)g * rows + k0) * 256 + col;
  unsigned short v[8];
#pragma unroll
  for (int j = 0; j < 8; ++j) v[j] = f2bf(src[(size_t)j * 256] * s);
  uint4 o;
  o.x = v[0] | ((unsigned)v[1] << 16);
  o.y = v[2] | ((unsigned)v[3] << 16);
  o.z = v[4] | ((unsigned)v[5] << 16);
  o.w = v[6] | ((unsigned)v[7] << 16);
  ((uint4*)dst)[gid] = o;
}

static __device__ __forceinline__ bf16x8 cvt8(float4 f0, float4 f1) {
  uint4 o;
  o.x = f2bf(f0.x) | ((unsigned)f2bf(f0.y) << 16);
  o.y = f2bf(f0.z) | ((unsigned)f2bf(f0.w) << 16);
  o.z = f2bf(f1.x) | ((unsigned)f2bf(f1.y) << 16);
  o.w = f2bf(f1.z) | ((unsigned)f2bf(f1.w) << 16);
  FragU f; f.u = o; return f.v;
}

// ---------------- Xg GEMM (chunked over time): A gathered on the fly ------------------
// LAYER 0: A row = x[grow] (dir1: x[rev]);  LAYER 1: A row = concat(states) per dir.
// Writes Xg[dir][chunkT*64][768] f32 with pre-scaled bias folded in.
template<int LAYER>
__global__ __launch_bounds__(256)
void gemm_xg_kernel(const float* __restrict__ x,
                    const unsigned short* __restrict__ fs0,
                    const unsigned short* __restrict__ bs0,
                    const unsigned short* __restrict__ Bp,
                    const float* __restrict__ bias_fw,
                    const float* __restrict__ bias_bw,
                    float* __restrict__ Xg, int t0, int chunkT)
{
  constexpr int KT = (LAYER == 0) ? 8 : 16;
  int dir = blockIdx.z;
  int lane = threadIdx.x & 63;
  int w = threadIdx.x >> 6;
  int ww = w >> 1, wc = w & 1;
  int mt0 = blockIdx.x * 8 + ww * 4;
  int nt0 = blockIdx.y * 8 + wc * 4;
  const uint4* B = (const uint4*)Bp + (size_t)dir * 48 * KT * 64;
  const int arow = lane & 15;
  const int k0b = ((lane >> 4) << 3);

  f32x4 acc[4][4] = {};
#pragma unroll
  for (int kt = 0; kt < KT; ++kt) {
    int k0 = kt * 32 + k0b;
    bf16x8 a[4], b[4];
#pragma unroll
    for (int i = 0; i < 4; ++i) {
      int grow = t0 * 64 + (mt0 + i) * 16 + arow;
      if (LAYER == 0) {
        int gr = dir ? revrow(grow) : grow;
        const float4* s = (const float4*)(x + (size_t)gr * 256 + k0);
        a[i] = cvt8(s[0], s[1]);
      } else {
        const unsigned short* base; int r2 = grow, kk = k0;
        if (k0 < 256) { base = dir ? bs0 : fs0; }
        else          { base = dir ? fs0 : bs0; r2 = revrow(grow); kk = k0 - 256; }
        a[i] = *(const bf16x8*)(base + (size_t)r2 * 256 + kk);
      }
    }
#pragma unroll
    for (int j = 0; j < 4; ++j) b[j] = ld_frag(B + ((size_t)(nt0 + j) * KT + kt) * 64 + lane);
#pragma unroll
    for (int i = 0; i < 4; ++i)
#pragma unroll
      for (int j = 0; j < 4; ++j)
        acc[i][j] = __builtin_amdgcn_mfma_f32_16x16x32_bf16(a[i], b[j], acc[i][j], 0, 0, 0);
  }

  const float* bias = dir ? bias_bw : bias_fw;
  float* C = Xg + (size_t)dir * chunkT * 64 * 768;
  int rbase = blockIdx.x * 128 + ww * 64 + ((lane >> 4) << 2);
#pragma unroll
  for (int j = 0; j < 4; ++j) {
    int col = (nt0 + j) * 16 + (lane & 15);
    int g = col >> 8, cc = col & 255;
    float bv = ((g == 1) ? S_C : S_RZ) * bias[g * 256 + cc];
#pragma unroll
    for (int i = 0; i < 4; ++i)
#pragma unroll
      for (int r = 0; r < 4; ++r)
        C[(size_t)(rbase + i * 16 + r) * 768 + col] = acc[i][j][r] + bv;
  }
}

// ---------------- persistent recurrent GRU kernel (one layer, both dirs, chunked) -----
// grid (4, 2): blockIdx.x = batch block (16 rows), blockIdx.y = dir. 512 threads = 8 waves.
template<int LAYER>
__global__ __launch_bounds__(512, 1)
void gru_kernel(const float* __restrict__ Xg,            // [dir][chunkT*64][768]
                const uint4* __restrict__ whrz_fw, const uint4* __restrict__ whrz_bw, // [32][8][64]
                const uint4* __restrict__ whc_fw,  const uint4* __restrict__ whc_bw,  // [16][8][64]
                unsigned short* __restrict__ sfw_bf, unsigned short* __restrict__ sbw_bf,
                float* __restrict__ out,
                float* __restrict__ hstate, float* __restrict__ dout_h,
                int t0, int chunkT)
{
  const int dir = blockIdx.y;
  const int row0 = blockIdx.x * 16;
  const int tid = threadIdx.x;
  const int lane = tid & 63;
  const int w = tid >> 6;

  __shared__ __align__(16) unsigned short h_bf[16 * 256];   // swizzled
  __shared__ __align__(16) unsigned short rh_bf[16 * 256];  // swizzled
  __shared__ __align__(16) float h_f[16 * 256];
  __shared__ __align__(16) float z_f[16 * 256];

  const uint4* whrzp = dir ? whrz_bw : whrz_fw;
  const uint4* whcp  = dir ? whc_bw  : whc_fw;

  bf16x8 wrz[4][8], whc[2][8];
#pragma unroll
  for (int nt = 0; nt < 4; ++nt)
#pragma unroll
    for (int kt = 0; kt < 8; ++kt)
      wrz[nt][kt] = ld_frag(whrzp + ((size_t)(w * 4 + nt) * 8 + kt) * 64 + lane);
#pragma unroll
  for (int nt = 0; nt < 2; ++nt)
#pragma unroll
    for (int kt = 0; kt < 8; ++kt)
      whc[nt][kt] = ld_frag(whcp + ((size_t)(w * 2 + nt) * 8 + kt) * 64 + lane);

  float* hst = hstate + (size_t)(dir * 4 + blockIdx.x) * 4096;
  for (int i = tid; i < 16 * 256; i += 512) {
    int rr = i >> 8, cc = i & 255;
    float v = (t0 == 0) ? 0.0f : hst[i];
    h_f[i] = v;
    int cb = cc * 2;
    int byt = rr * 512 + (((cb & ~15) ^ ((rr & 7) << 4)) | (cb & 15));
    *(unsigned short*)((char*)h_bf + byt) = f2bf(v);
  }
  __syncthreads();

  const int crow = ((lane >> 4) << 2);   // C/D row base
  const int ccol = lane & 15;
  const bool is_r = (w < 4);
  const float* XgD = Xg + (size_t)dir * chunkT * 64 * 768;
  const int afrow = lane & 15;           // A-frag row
  const int afcoff = ((lane >> 4) << 4); // A-frag 16B chunk offset within 64B k-tile
  unsigned short* sp_bf = dir ? sbw_bf : sfw_bf;
  const int coff = dir ? 256 : 0;

#pragma unroll 1
  for (int t = t0; t < t0 + chunkT; ++t) {
    const float* Xrow = XgD + (size_t)((t - t0) * 64 + row0) * 768;

    // ---------- phase A: rz = h @ Whrz (+x-part), r->rh, z->LDS ----------
    float xg[4][4];
#pragma unroll
    for (int nt = 0; nt < 4; ++nt) {
      int cl = (w * 4 + nt) * 16 + ccol;          // rz col 0..511
      int cx = cl + (is_r ? 0 : 256);             // Xg col ([r|c|z] order)
#pragma unroll
      for (int r = 0; r < 4; ++r)
        xg[nt][r] = Xrow[(size_t)(crow + r) * 768 + cx];
    }
    f32x4 acc[4] = {};
#pragma unroll
    for (int kt = 0; kt < 8; ++kt) {
      int byt = afrow * 512 + ((kt * 64 + afcoff) ^ ((afrow & 7) << 4));
      bf16x8 a = *(const bf16x8*)((const char*)h_bf + byt);
#pragma unroll
      for (int nt = 0; nt < 4; ++nt)
        acc[nt] = __builtin_amdgcn_mfma_f32_16x16x32_bf16(a, wrz[nt][kt], acc[nt], 0, 0, 0);
    }
#pragma unroll
    for (int nt = 0; nt < 4; ++nt) {
      int cl = (w * 4 + nt) * 16 + ccol;
#pragma unroll
      for (int r = 0; r < 4; ++r) {
        int rr = crow + r;
        float v = acc[nt][r] + xg[nt][r];
        float gate = __builtin_amdgcn_rcpf(1.0f + __builtin_amdgcn_exp2f(v)); // sigmoid
        if (is_r) {
          float h = h_f[rr * 256 + cl];
          int cb = cl * 2;
          int byt = rr * 512 + (((cb & ~15) ^ ((rr & 7) << 4)) | (cb & 15));
          *(unsigned short*)((char*)rh_bf + byt) = f2bf(gate * h);
        } else {
          z_f[rr * 256 + (cl - 256)] = gate;
        }
      }
    }
    __syncthreads();

    // ---------- phase B: cand = tanh-form((r*h) @ Whc + x-part), update h ----------
    float xg2[2][4];
#pragma unroll
    for (int nt = 0; nt < 2; ++nt) {
      int c2 = (w * 2 + nt) * 16 + ccol;          // cand col 0..255
#pragma unroll
      for (int r = 0; r < 4; ++r)
        xg2[nt][r] = Xrow[(size_t)(crow + r) * 768 + 256 + c2];
    }
    f32x4 acc2[2] = {};
#pragma unroll
    for (int kt = 0; kt < 8; ++kt) {
      int byt = afrow * 512 + ((kt * 64 + afcoff) ^ ((afrow & 7) << 4));
      bf16x8 a = *(const bf16x8*)((const char*)rh_bf + byt);
#pragma unroll
      for (int nt = 0; nt < 2; ++nt)
        acc2[nt] = __builtin_amdgcn_mfma_f32_16x16x32_bf16(a, whc[nt][kt], acc2[nt], 0, 0, 0);
    }
    int gbase = (LAYER == 1 && dir) ? ((T_STEPS - 1 - t) * 64 + row0) : (t * 64 + row0);
#pragma unroll
    for (int nt = 0; nt < 2; ++nt) {
      int c2 = (w * 2 + nt) * 16 + ccol;
#pragma unroll
      for (int r = 0; r < 4; ++r) {
        int rr = crow + r;
        float v = acc2[nt][r] + xg2[nt][r];
        float cand = __builtin_amdgcn_rcpf(1.0f + __builtin_amdgcn_exp2f(v)) * 2.0f - 1.0f;
        float z = z_f[rr * 256 + c2];
        float h = h_f[rr * 256 + c2];
        float hn = cand + z * (h - cand);
        h_f[rr * 256 + c2] = hn;
        int cb = c2 * 2;
        int byt = rr * 512 + (((cb & ~15) ^ ((rr & 7) << 4)) | (cb & 15));
        *(unsigned short*)((char*)h_bf + byt) = f2bf(hn);
        if (LAYER == 0) sp_bf[(size_t)(gbase + rr) * 256 + c2] = f2bf(hn);
        else            out[(size_t)(gbase + rr) * 512 + coff + c2] = hn;
      }
    }
    __syncthreads();
  }

  // persist h; on last chunk also write fh/bh (layer-major)
  for (int i = tid; i < 16 * 256; i += 512) hst[i] = h_f[i];
  if (t0 + chunkT == T_STEPS) {
    float* dst = dout_h + (dir ? 32768 : 0) + (size_t)LAYER * 16384;
    for (int i = tid; i < 16 * 256; i += 512) {
      int rr = i >> 8, cc = i & 255;
      dst[(size_t)(row0 + rr) * 256 + cc] = h_f[i];
    }
  }
}

__global__ void diag_kernel(float* out, float v) { out[0] = v; }

// --------------------------------------------------------------------------------------
extern "C" void kernel_launch(void* const* d_in, const int* in_sizes, int n_in,
                              void* d_out, int out_size, void* d_ws, size_t ws_size,
                              hipStream_t stream) {
  const float* x     = (const float*)d_in[0];
  const float* fw_W0 = (const float*)d_in[2];
  const float* fw_b0 = (const float*)d_in[3];
  const float* fw_W1 = (const float*)d_in[4];
  const float* fw_b1 = (const float*)d_in[5];
  const float* bw_W0 = (const float*)d_in[6];
  const float* bw_b0 = (const float*)d_in[7];
  const float* bw_W1 = (const float*)d_in[8];
  const float* bw_b1 = (const float*)d_in[9];

  char* ws = (char*)d_ws;
  size_t off = 0;
  auto alloc = [&](size_t bytes) -> char* {
    char* p = ws + off; off += (bytes + 255) & ~(size_t)255; return p;
  };
  unsigned short* Wx0p  = (unsigned short*)alloc(2ull * 48 * 8 * 64 * 8 * 2);
  unsigned short* Wx1p  = (unsigned short*)alloc(2ull * 48 * 16 * 64 * 8 * 2);
  unsigned short* Whrz0 = (unsigned short*)alloc(2ull * 32 * 8 * 64 * 8 * 2);
  unsigned short* Whc0  = (unsigned short*)alloc(2ull * 16 * 8 * 64 * 8 * 2);
  unsigned short* Whrz1 = (unsigned short*)alloc(2ull * 32 * 8 * 64 * 8 * 2);
  unsigned short* Whc1  = (unsigned short*)alloc(2ull * 16 * 8 * 64 * 8 * 2);
  unsigned short* fs0   = (unsigned short*)alloc((size_t)TB * 256 * 2);
  unsigned short* bs0   = (unsigned short*)alloc((size_t)TB * 256 * 2);
  float* hstate         = (float*)alloc(2ull * 4 * 16 * 256 * 4);

  // pick largest time-chunk whose Xg f32 buffer fits
  int chunkT = 0;
  for (int ct = 512; ct >= 8; ct >>= 1) {
    if (off + (size_t)ct * 2 * 64 * 768 * 4 <= ws_size) { chunkT = ct; break; }
  }
  float* out = (float*)d_out;
  if (chunkT == 0) {  // workspace hopeless — leave a sentinel for diagnosis
    diag_kernel<<<1, 1, 0, stream>>>(out, 12345.0f);
    return;
  }
  float* Xg = (float*)alloc((size_t)chunkT * 2 * 64 * 768 * 4);
  float* dout_h = out + (size_t)TB * 512;

  auto packw = [&](const float* W, int rows, int kb, int ntl, int ktl, int mode, unsigned short* dst) {
    int total = ntl * ktl * 64;
    pack_w_kernel<<<(total + 255) / 256, 256, 0, stream>>>(W, rows, kb, ntl, ktl, mode, dst);
  };
  packw(fw_W0, 512, 0,   48, 8,  0, Wx0p);
  packw(bw_W0, 512, 0,   48, 8,  0, Wx0p + 48 * 8 * 64 * 8);
  packw(fw_W1, 768, 0,   48, 16, 0, Wx1p);
  packw(bw_W1, 768, 0,   48, 16, 0, Wx1p + 48 * 16 * 64 * 8);
  packw(fw_W0, 512, 256, 32, 8,  1, Whrz0);
  packw(bw_W0, 512, 256, 32, 8,  1, Whrz0 + 32 * 8 * 64 * 8);
  packw(fw_W0, 512, 256, 16, 8,  2, Whc0);
  packw(bw_W0, 512, 256, 16, 8,  2, Whc0 + 16 * 8 * 64 * 8);
  packw(fw_W1, 768, 512, 32, 8,  1, Whrz1);
  packw(bw_W1, 768, 512, 32, 8,  1, Whrz1 + 32 * 8 * 64 * 8);
  packw(fw_W1, 768, 512, 16, 8,  2, Whc1);
  packw(bw_W1, 768, 512, 16, 8,  2, Whc1 + 16 * 8 * 64 * 8);

  dim3 ggrid(chunkT / 2, 6, 2);
  dim3 rgrid(4, 2);
  // layer 0
  for (int t0 = 0; t0 < T_STEPS; t0 += chunkT) {
    gemm_xg_kernel<0><<<ggrid, 256, 0, stream>>>(x, nullptr, nullptr, Wx0p, fw_b0, bw_b0, Xg, t0, chunkT);
    gru_kernel<0><<<rgrid, 512, 0, stream>>>(Xg,
        (const uint4*)Whrz0, (const uint4*)(Whrz0 + 32 * 8 * 64 * 8),
        (const uint4*)Whc0,  (const uint4*)(Whc0 + 16 * 8 * 64 * 8),
        fs0, bs0, nullptr, hstate, dout_h, t0, chunkT);
  }
  // layer 1
  for (int t0 = 0; t0 < T_STEPS; t0 += chunkT) {
    gemm_xg_kernel<1><<<ggrid, 256, 0, stream>>>(nullptr, fs0, bs0, Wx1p, fw_b1, bw_b1, Xg, t0, chunkT);
    gru_kernel<1><<<rgrid, 512, 0, stream>>>(Xg,
        (const uint4*)Whrz1, (const uint4*)(Whrz1 + 32 * 8 * 64 * 8),
        (const uint4*)Whc1,  (const uint4*)(Whc1 + 16 * 8 * 64 * 8),
        nullptr, nullptr, out, hstate, dout_h, t0, chunkT);
  }
}